// Round 9
// baseline (192.232 us; speedup 1.0000x reference)
//
#include <hip/hip_runtime.h>
#include <hip/hip_bf16.h>

// B=256, C_IN=6, L=512, C1=32, C2=D=64, NCLASS=10.
// Megakernel: one block per batch (1024 thr = 16 waves, 32 L-rows/wave).
// conv1 -> conv2(MFMA) -> bn2 -> q,k (regs as A-frags), v^T (wave LDS slab)
// -> 2-pass flash attention (256 keys/pass; K pushed to shared frag buffer,
// V read cross-wave from owner slabs) -> pooled -> fc, all in one kernel.
// ws: only prepped bf16 weights (w2p k'-packed, wqp x0.125, wkp, wvp).

#define NB 256
#define LL 512
#define CIN 6
#define C1 32
#define NCLASS 10

typedef __bf16 bf16x8 __attribute__((ext_vector_type(8)));
typedef float f32x4 __attribute__((ext_vector_type(4)));
typedef unsigned short us4 __attribute__((ext_vector_type(4)));

static __device__ __forceinline__ unsigned short f2b(float f) {
    __bf16 h = (__bf16)f;                       // RNE f32->bf16
    return __builtin_bit_cast(unsigned short, h);
}

// ---------------------------------------------------------------------------
// Kernel P: one-time weight conversion to bf16 (~3 us).
// ---------------------------------------------------------------------------
__global__ __launch_bounds__(256) void prep_weights(
    const float* __restrict__ w2, const float* __restrict__ wq,
    const float* __restrict__ wk, const float* __restrict__ wv,
    unsigned short* __restrict__ w2p, unsigned short* __restrict__ wqp,
    unsigned short* __restrict__ wkp, unsigned short* __restrict__ wvp)
{
    const int t = threadIdx.x;
    for (int idx = t; idx < 2048; idx += 256) {
        int c2 = idx >> 5, ci = idx & 31;
        const float* wp = w2 + c2 * 96 + ci * 3;
        w2p[c2 * 96 +      ci] = f2b(wp[0]);
        w2p[c2 * 96 + 32 + ci] = f2b(wp[1]);
        w2p[c2 * 96 + 64 + ci] = f2b(wp[2]);
    }
    for (int idx = t; idx < 4096; idx += 256) {
        wqp[idx] = f2b(wq[idx] * 0.125f);       // fold 1/sqrt(64), exact
        wkp[idx] = f2b(wk[idx]);
        wvp[idx] = f2b(wv[idx]);
    }
}

// ---------------------------------------------------------------------------
// Megakernel.
// ---------------------------------------------------------------------------
__global__ __launch_bounds__(1024) void fused_all(
    const float* __restrict__ x,
    const float* __restrict__ w1, const float* __restrict__ cb1,
    const float* __restrict__ g1, const float* __restrict__ be1,
    const float* __restrict__ m1, const float* __restrict__ v1,
    const float* __restrict__ cb2, const float* __restrict__ g2,
    const float* __restrict__ be2, const float* __restrict__ m2,
    const float* __restrict__ v2,
    const float* __restrict__ bq, const float* __restrict__ bk,
    const float* __restrict__ bvp,
    const unsigned short* __restrict__ w2p, const unsigned short* __restrict__ wqp,
    const unsigned short* __restrict__ wkp, const unsigned short* __restrict__ wvp,
    const float* __restrict__ fcw, const float* __restrict__ fcb,
    float* __restrict__ outp)
{
    const int b = blockIdx.x;
    const int t = threadIdx.x;
    const int w = t >> 6, lane = t & 63, quad = lane >> 4, lc = lane & 15;

    // LDS: slabs 16x5120 | Kb 32768 | Ps 16x1280 | red 4096 | pooled 256
    __shared__ __align__(16) char smem[81920 + 32768 + 20480 + 4096 + 256];
    char* myslab = smem + w * 5120;
    // slab timeline (wave-private, in-order DS pipe, no barriers):
    //   xsl[6][36] f32 @0 + h1sl[34][40] bf16 @880  ->  Ts[32][72] bf16 @0
    //   ->  Vs[64][40] bf16 @0 (persists through attention)
    float*          xsl  = (float*)myslab;
    unsigned short* h1sl = (unsigned short*)(myslab + 880);
    unsigned short* Ts   = (unsigned short*)myslab;
    unsigned short* Vs   = (unsigned short*)myslab;
    unsigned short* Kb   = (unsigned short*)(smem + 81920);
    unsigned short* Ps   = (unsigned short*)(smem + 81920 + 32768 + w * 1280);
    float* red    = (float*)(smem + 81920 + 32768 + 20480);   // [16][64]
    float* pooled = (float*)(smem + 81920 + 32768 + 20480 + 4096);

    // ---- P0: x slice for this wave's rows (halo 2) -----------------------
    for (int i = lane; i < CIN * 36; i += 64) {
        int c = i / 36, j = i % 36;
        int l = w * 32 - 2 + j;
        xsl[c * 36 + j] = (l >= 0 && l < LL) ? x[((size_t)b * CIN + c) * LL + l] : 0.f;
    }

    // ---- P1: conv1 + bn1 + relu -> h1sl[j][ci], pos = w*32-1+j, j<34 -----
    for (int i = lane; i < 34 * C1; i += 64) {
        int j = i >> 5, c = i & 31;
        int pos = w * 32 - 1 + j;
        float y = 0.f;
        if (pos >= 0 && pos < LL) {
            float inv = g1[c] * rsqrtf(v1[c] + 1e-5f);
            float sh  = be1[c] + (cb1[c] - m1[c]) * inv;
            float acc = 0.f;
            #pragma unroll
            for (int ci = 0; ci < CIN; ci++) {
                const float* wp = w1 + (c * CIN + ci) * 3;
                acc += xsl[ci * 36 + j] * wp[0] + xsl[ci * 36 + j + 1] * wp[1]
                     + xsl[ci * 36 + j + 2] * wp[2];
            }
            y = acc * inv + sh;
            y = y > 0.f ? y : 0.f;
        }
        h1sl[j * 40 + c] = f2b(y);
    }

    // ---- P2: conv2 as GEMM (M=64 c2, N=32 rows, K=96; k'=dl*32+ci) -------
    bf16x8 bX[2][3], aW2[4][3];
    #pragma unroll
    for (int rt = 0; rt < 2; rt++)
        #pragma unroll
        for (int kc = 0; kc < 3; kc++)
            bX[rt][kc] = *(const bf16x8*)&h1sl[(rt * 16 + lc + kc) * 40 + quad * 8];
    #pragma unroll
    for (int nt = 0; nt < 4; nt++)
        #pragma unroll
        for (int kc = 0; kc < 3; kc++)
            aW2[nt][kc] = *(const bf16x8*)(w2p + (nt * 16 + lc) * 96 + kc * 32 + quad * 8);

    f32x4 acc2[4][2];
    #pragma unroll
    for (int nt = 0; nt < 4; nt++)
        #pragma unroll
        for (int rt = 0; rt < 2; rt++) {
            f32x4 a = {0.f, 0.f, 0.f, 0.f};
            a = __builtin_amdgcn_mfma_f32_16x16x32_bf16(aW2[nt][0], bX[rt][0], a, 0, 0, 0);
            a = __builtin_amdgcn_mfma_f32_16x16x32_bf16(aW2[nt][1], bX[rt][1], a, 0, 0, 0);
            acc2[nt][rt] = __builtin_amdgcn_mfma_f32_16x16x32_bf16(aW2[nt][2], bX[rt][2], a, 0, 0, 0);
        }

    // ---- P3a: bn2 + relu -> Ts[row][c2] (x/h1 dead; same-wave in-order) --
    #pragma unroll
    for (int nt = 0; nt < 4; nt++) {
        const float4 gv  = *(const float4*)&g2[nt * 16 + quad * 4];
        const float4 vv  = *(const float4*)&v2[nt * 16 + quad * 4];
        const float4 bev = *(const float4*)&be2[nt * 16 + quad * 4];
        const float4 cbv = *(const float4*)&cb2[nt * 16 + quad * 4];
        const float4 mv  = *(const float4*)&m2[nt * 16 + quad * 4];
        float inv[4], sh[4];
        inv[0] = gv.x * rsqrtf(vv.x + 1e-5f); sh[0] = bev.x + (cbv.x - mv.x) * inv[0];
        inv[1] = gv.y * rsqrtf(vv.y + 1e-5f); sh[1] = bev.y + (cbv.y - mv.y) * inv[1];
        inv[2] = gv.z * rsqrtf(vv.z + 1e-5f); sh[2] = bev.z + (cbv.z - mv.z) * inv[2];
        inv[3] = gv.w * rsqrtf(vv.w + 1e-5f); sh[3] = bev.w + (cbv.w - mv.w) * inv[3];
        #pragma unroll
        for (int rt = 0; rt < 2; rt++) {
            us4 pk;
            #pragma unroll
            for (int r = 0; r < 4; r++) {
                float y = acc2[nt][rt][r] * inv[r] + sh[r];
                y = y > 0.f ? y : 0.f;
                pk[r] = f2b(y);
            }
            *(us4*)&Ts[(rt * 16 + lc) * 72 + nt * 16 + quad * 4] = pk;
        }
    }
    bf16x8 aH[2][2];
    #pragma unroll
    for (int rt = 0; rt < 2; rt++)
        #pragma unroll
        for (int kc = 0; kc < 2; kc++)
            aH[rt][kc] = *(const bf16x8*)&Ts[(rt * 16 + lc) * 72 + kc * 32 + quad * 8];

    // ---- P3b: q then k, kept as A-frags in registers ----------------------
    bf16x8 aQ[2][2], aK[2][2];
    for (int p = 0; p < 2; p++) {
        const unsigned short* wsrc = p ? wkp : wqp;
        const float* bsrc = p ? bk : bq;
        const float bscl = p ? 1.0f : 0.125f;
        #pragma unroll
        for (int nt = 0; nt < 4; nt++) {
            bf16x8 aW[2];
            #pragma unroll
            for (int kc = 0; kc < 2; kc++)
                aW[kc] = *(const bf16x8*)(wsrc + (nt * 16 + lc) * 64 + kc * 32 + quad * 8);
            float4 bb = *(const float4*)&bsrc[nt * 16 + quad * 4];
            bb.x *= bscl; bb.y *= bscl; bb.z *= bscl; bb.w *= bscl;
            #pragma unroll
            for (int rt = 0; rt < 2; rt++) {
                f32x4 a = {0.f, 0.f, 0.f, 0.f};
                a = __builtin_amdgcn_mfma_f32_16x16x32_bf16(aW[0], aH[rt][0], a, 0, 0, 0);
                a = __builtin_amdgcn_mfma_f32_16x16x32_bf16(aW[1], aH[rt][1], a, 0, 0, 0);
                us4 pk;
                pk[0] = f2b(a[0] + bb.x); pk[1] = f2b(a[1] + bb.y);
                pk[2] = f2b(a[2] + bb.z); pk[3] = f2b(a[3] + bb.w);
                *(us4*)&Ts[(rt * 16 + lc) * 72 + nt * 16 + quad * 4] = pk;
            }
        }
        #pragma unroll
        for (int rt = 0; rt < 2; rt++)
            #pragma unroll
            for (int kc = 0; kc < 2; kc++) {
                bf16x8 fr = *(const bf16x8*)&Ts[(rt * 16 + lc) * 72 + kc * 32 + quad * 8];
                if (p == 0) aQ[rt][kc] = fr; else aK[rt][kc] = fr;
            }
    }

    // ---- P3c: v -> Vs[d][key] in this wave's slab (persists) -------------
    #pragma unroll
    for (int nt = 0; nt < 4; nt++) {
        bf16x8 bW[2];
        #pragma unroll
        for (int kc = 0; kc < 2; kc++)
            bW[kc] = *(const bf16x8*)(wvp + (nt * 16 + lc) * 64 + kc * 32 + quad * 8);
        const float bvv = bvp[nt * 16 + lc];
        #pragma unroll
        for (int rt = 0; rt < 2; rt++) {
            f32x4 a = {0.f, 0.f, 0.f, 0.f};
            a = __builtin_amdgcn_mfma_f32_16x16x32_bf16(aH[rt][0], bW[0], a, 0, 0, 0);
            a = __builtin_amdgcn_mfma_f32_16x16x32_bf16(aH[rt][1], bW[1], a, 0, 0, 0);
            us4 pk;
            pk[0] = f2b(a[0] + bvv); pk[1] = f2b(a[1] + bvv);
            pk[2] = f2b(a[2] + bvv); pk[3] = f2b(a[3] + bvv);
            *(us4*)&Vs[(nt * 16 + lc) * 40 + rt * 16 + quad * 4] = pk;
        }
    }

    // ---- attention: 2 passes of 256 keys ---------------------------------
    f32x4 outacc[2][4];
    #pragma unroll
    for (int rt = 0; rt < 2; rt++)
        #pragma unroll
        for (int dt = 0; dt < 4; dt++) outacc[rt][dt] = (f32x4){0.f, 0.f, 0.f, 0.f};
    float den[2][4] = {{0.f, 0.f, 0.f, 0.f}, {0.f, 0.f, 0.f, 0.f}};

    for (int p = 0; p < 2; p++) {
        if ((w >> 3) == p) {               // owner waves push K A-frags
            const int cc = w & 7;
            #pragma unroll
            for (int rt = 0; rt < 2; rt++)
                #pragma unroll
                for (int kc = 0; kc < 2; kc++)
                    *(bf16x8*)&Kb[(((cc * 2 + rt) * 2 + kc) << 9) + lane * 8] = aK[rt][kc];
        }
        __syncthreads();

        for (int cc = 0; cc < 8; cc++) {   // 32-key chunks
            const unsigned short* vsl = (const unsigned short*)(smem + (p * 8 + cc) * 5120);
            bf16x8 bK[2][2];
            #pragma unroll
            for (int nt = 0; nt < 2; nt++)
                #pragma unroll
                for (int kc = 0; kc < 2; kc++)
                    bK[nt][kc] = *(const bf16x8*)&Kb[(((cc * 2 + nt) * 2 + kc) << 9) + lane * 8];
            bf16x8 bV[4];
            #pragma unroll
            for (int dt = 0; dt < 4; dt++)
                bV[dt] = *(const bf16x8*)&vsl[(dt * 16 + lc) * 40 + quad * 8];
            #pragma unroll
            for (int rt = 0; rt < 2; rt++) {
                #pragma unroll
                for (int nt = 0; nt < 2; nt++) {
                    f32x4 sv = {0.f, 0.f, 0.f, 0.f};
                    sv = __builtin_amdgcn_mfma_f32_16x16x32_bf16(aQ[rt][0], bK[nt][0], sv, 0, 0, 0);
                    sv = __builtin_amdgcn_mfma_f32_16x16x32_bf16(aQ[rt][1], bK[nt][1], sv, 0, 0, 0);
                    #pragma unroll
                    for (int reg = 0; reg < 4; reg++) {
                        float pr = __expf(sv[reg]);       // q pre-scaled by 1/8
                        den[rt][reg] += pr;
                        Ps[(quad * 4 + reg) * 40 + nt * 16 + lc] = f2b(pr);
                    }
                }
                bf16x8 aP = *(const bf16x8*)&Ps[lc * 40 + quad * 8];
                #pragma unroll
                for (int dt = 0; dt < 4; dt++)
                    outacc[rt][dt] = __builtin_amdgcn_mfma_f32_16x16x32_bf16(
                        aP, bV[dt], outacc[rt][dt], 0, 0, 0);
            }
        }
        __syncthreads();                   // readers done before Kb reuse
    }

    // ---- epilogue: den reduce, pooled over the wave's 32 rows ------------
    #pragma unroll
    for (int rt = 0; rt < 2; rt++)
        #pragma unroll
        for (int reg = 0; reg < 4; reg++) {
            float d2 = den[rt][reg];
            d2 += __shfl_xor(d2, 1);  d2 += __shfl_xor(d2, 2);
            d2 += __shfl_xor(d2, 4);  d2 += __shfl_xor(d2, 8);
            den[rt][reg] = d2;
        }
    #pragma unroll
    for (int dt = 0; dt < 4; dt++) {
        float ps = 0.f;
        #pragma unroll
        for (int rt = 0; rt < 2; rt++)
            #pragma unroll
            for (int reg = 0; reg < 4; reg++)
                ps += outacc[rt][dt][reg] / den[rt][reg];
        ps += __shfl_xor(ps, 16);
        ps += __shfl_xor(ps, 32);
        if (quad == 0) red[w * 64 + dt * 16 + lc] = ps;
    }
    __syncthreads();
    if (t < 64) {
        float s = 0.f;
        #pragma unroll
        for (int ww = 0; ww < 16; ww++) s += red[ww * 64 + t];
        pooled[t] = s * (1.0f / 512.0f);
    }
    __syncthreads();
    if (t < NCLASS) {
        float acc = fcb[t];
        #pragma unroll
        for (int d = 0; d < 64; d++) acc += pooled[d] * fcw[t * 64 + d];
        outp[b * NCLASS + t] = acc;
    }
}

// ---------------------------------------------------------------------------
extern "C" void kernel_launch(void* const* d_in, const int* in_sizes, int n_in,
                              void* d_out, int out_size, void* d_ws, size_t ws_size,
                              hipStream_t stream)
{
    const float* x   = (const float*)d_in[0];
    const float* w1  = (const float*)d_in[1];
    const float* cb1 = (const float*)d_in[2];
    const float* g1  = (const float*)d_in[3];
    const float* be1 = (const float*)d_in[4];
    const float* m1  = (const float*)d_in[5];
    const float* v1  = (const float*)d_in[6];
    const float* w2  = (const float*)d_in[7];
    const float* cb2 = (const float*)d_in[8];
    const float* g2  = (const float*)d_in[9];
    const float* be2 = (const float*)d_in[10];
    const float* m2  = (const float*)d_in[11];
    const float* v2  = (const float*)d_in[12];
    const float* wq  = (const float*)d_in[13];
    const float* bq  = (const float*)d_in[14];
    const float* wk  = (const float*)d_in[15];
    const float* bk  = (const float*)d_in[16];
    const float* wv  = (const float*)d_in[17];
    const float* bv  = (const float*)d_in[18];
    const float* fcw = (const float*)d_in[19];
    const float* fcb = (const float*)d_in[20];
    float* out = (float*)d_out;

    char* ws = (char*)d_ws;
    unsigned short* w2p = (unsigned short*)(ws);            // 12,288 B
    unsigned short* wqp = (unsigned short*)(ws + 12288u);   // 8,192 B
    unsigned short* wkp = (unsigned short*)(ws + 20480u);   // 8,192 B
    unsigned short* wvp = (unsigned short*)(ws + 28672u);   // 8,192 B

    prep_weights<<<dim3(1), 256, 0, stream>>>(w2, wq, wk, wv, w2p, wqp, wkp, wvp);
    fused_all<<<dim3(NB), 1024, 0, stream>>>(x, w1, cb1, g1, be1, m1, v1,
                                             cb2, g2, be2, m2, v2,
                                             bq, bk, bv,
                                             w2p, wqp, wkp, wvp,
                                             fcw, fcb, out);
}

// Round 11
// 149.072 us; speedup vs baseline: 1.2895x; 1.2895x over previous
//
#include <hip/hip_runtime.h>
#include <hip/hip_bf16.h>

// B=256, C_IN=6, L=512, C1=32, C2=D=64, NCLASS=10.
// Megakernel v2.1: one block per batch (1024 thr = 16 waves, 32 L-rows/wave).
// Fully distributed K/V: each wave's LDS slab holds its 32 keys' K-frags and
// V-frags in lane-linear order; attention is ONE pass over 16 slabs with zero
// barriers (same-address broadcast reads). No q/k/v HBM traffic, no spills
// (launch_bounds(1024,4) -> 128 VGPRs).
// v2.1 fix: V frag stride is 512 shorts (was 1024 -> clobbered Ps/next slab).
// ws: only prepped bf16 weights (w2p k'-packed, wqp x0.125, wkp, wvp).

#define NB 256
#define LL 512
#define CIN 6
#define C1 32
#define NCLASS 10
#define SLAB 9472

typedef __bf16 bf16x8 __attribute__((ext_vector_type(8)));
typedef float f32x4 __attribute__((ext_vector_type(4)));
typedef unsigned short us4 __attribute__((ext_vector_type(4)));

static __device__ __forceinline__ unsigned short f2b(float f) {
    __bf16 h = (__bf16)f;                       // RNE f32->bf16
    return __builtin_bit_cast(unsigned short, h);
}

// ---------------------------------------------------------------------------
// Kernel P: one-time weight conversion to bf16 (~3 us).
// ---------------------------------------------------------------------------
__global__ __launch_bounds__(256) void prep_weights(
    const float* __restrict__ w2, const float* __restrict__ wq,
    const float* __restrict__ wk, const float* __restrict__ wv,
    unsigned short* __restrict__ w2p, unsigned short* __restrict__ wqp,
    unsigned short* __restrict__ wkp, unsigned short* __restrict__ wvp)
{
    const int t = threadIdx.x;
    for (int idx = t; idx < 2048; idx += 256) {
        int c2 = idx >> 5, ci = idx & 31;
        const float* wp = w2 + c2 * 96 + ci * 3;
        w2p[c2 * 96 +      ci] = f2b(wp[0]);
        w2p[c2 * 96 + 32 + ci] = f2b(wp[1]);
        w2p[c2 * 96 + 64 + ci] = f2b(wp[2]);
    }
    for (int idx = t; idx < 4096; idx += 256) {
        wqp[idx] = f2b(wq[idx] * 0.125f);       // fold 1/sqrt(64), exact
        wkp[idx] = f2b(wk[idx]);
        wvp[idx] = f2b(wv[idx]);
    }
}

// ---------------------------------------------------------------------------
// Megakernel v2.1.
// Slab layout per wave (9472 B), aliased phases:
//   conv:  xsl[6][36] f32 @0 (864) | h1sl[34][40] bf16 @880 (2720)
//          Ts[32][72] bf16 @4608 (4608)
//   attn:  Kf @0    (4096 B: 4 frags x 512 shorts, lane-linear)
//          Vf @4096 (4096 B: 4 frags x 512 shorts, lane-linear)
//          Ps @8192 ([16][40] bf16, 1280 B)
// Block extras: red[16][64] f32 @151552, pooled[64] f32 @155648. Total 155904.
// ---------------------------------------------------------------------------
__global__ __launch_bounds__(1024, 4) void fused_all(
    const float* __restrict__ x,
    const float* __restrict__ w1, const float* __restrict__ cb1,
    const float* __restrict__ g1, const float* __restrict__ be1,
    const float* __restrict__ m1, const float* __restrict__ v1,
    const float* __restrict__ cb2, const float* __restrict__ g2,
    const float* __restrict__ be2, const float* __restrict__ m2,
    const float* __restrict__ v2,
    const float* __restrict__ bq, const float* __restrict__ bk,
    const float* __restrict__ bvp,
    const unsigned short* __restrict__ w2p, const unsigned short* __restrict__ wqp,
    const unsigned short* __restrict__ wkp, const unsigned short* __restrict__ wvp,
    const float* __restrict__ fcw, const float* __restrict__ fcb,
    float* __restrict__ outp)
{
    const int b = blockIdx.x;
    const int t = threadIdx.x;
    const int w = t >> 6, lane = t & 63, quad = lane >> 4, lc = lane & 15;

    __shared__ __align__(16) char smem[155904];
    char* myslab = smem + w * SLAB;
    float*          xsl  = (float*)myslab;
    unsigned short* h1sl = (unsigned short*)(myslab + 880);
    unsigned short* Ts   = (unsigned short*)(myslab + 4608);
    unsigned short* Kf   = (unsigned short*)myslab;
    unsigned short* Vf   = (unsigned short*)(myslab + 4096);
    unsigned short* Ps   = (unsigned short*)(myslab + 8192);
    float* red    = (float*)(smem + 151552);
    float* pooled = (float*)(smem + 155648);

    // ---- P0: x slice for this wave's rows (halo 2) -----------------------
    for (int i = lane; i < CIN * 36; i += 64) {
        int c = i / 36, j = i % 36;
        int l = w * 32 - 2 + j;
        xsl[c * 36 + j] = (l >= 0 && l < LL) ? x[((size_t)b * CIN + c) * LL + l] : 0.f;
    }

    // ---- P1: conv1 + bn1 + relu -> h1sl[j][ci], pos = w*32-1+j, j<34 -----
    for (int i = lane; i < 34 * C1; i += 64) {
        int j = i >> 5, c = i & 31;
        int pos = w * 32 - 1 + j;
        float y = 0.f;
        if (pos >= 0 && pos < LL) {
            float inv = g1[c] * rsqrtf(v1[c] + 1e-5f);
            float sh  = be1[c] + (cb1[c] - m1[c]) * inv;
            float acc = 0.f;
            #pragma unroll
            for (int ci = 0; ci < CIN; ci++) {
                const float* wp = w1 + (c * CIN + ci) * 3;
                acc += xsl[ci * 36 + j] * wp[0] + xsl[ci * 36 + j + 1] * wp[1]
                     + xsl[ci * 36 + j + 2] * wp[2];
            }
            y = acc * inv + sh;
            y = y > 0.f ? y : 0.f;
        }
        h1sl[j * 40 + c] = f2b(y);
    }

    // ---- P2: conv2 as GEMM (M=64 c2, N=32 rows, K=96; k'=dl*32+ci) -------
    bf16x8 bX[2][3], aW2[4][3];
    #pragma unroll
    for (int rt = 0; rt < 2; rt++)
        #pragma unroll
        for (int kc = 0; kc < 3; kc++)
            bX[rt][kc] = *(const bf16x8*)&h1sl[(rt * 16 + lc + kc) * 40 + quad * 8];
    #pragma unroll
    for (int nt = 0; nt < 4; nt++)
        #pragma unroll
        for (int kc = 0; kc < 3; kc++)
            aW2[nt][kc] = *(const bf16x8*)(w2p + (nt * 16 + lc) * 96 + kc * 32 + quad * 8);

    f32x4 acc2[4][2];
    #pragma unroll
    for (int nt = 0; nt < 4; nt++)
        #pragma unroll
        for (int rt = 0; rt < 2; rt++) {
            f32x4 a = {0.f, 0.f, 0.f, 0.f};
            a = __builtin_amdgcn_mfma_f32_16x16x32_bf16(aW2[nt][0], bX[rt][0], a, 0, 0, 0);
            a = __builtin_amdgcn_mfma_f32_16x16x32_bf16(aW2[nt][1], bX[rt][1], a, 0, 0, 0);
            acc2[nt][rt] = __builtin_amdgcn_mfma_f32_16x16x32_bf16(aW2[nt][2], bX[rt][2], a, 0, 0, 0);
        }

    // ---- P3a: bn2 + relu -> Ts[row][c2] (same-wave in-order DS pipe) -----
    #pragma unroll
    for (int nt = 0; nt < 4; nt++) {
        const float4 gv  = *(const float4*)&g2[nt * 16 + quad * 4];
        const float4 vv  = *(const float4*)&v2[nt * 16 + quad * 4];
        const float4 bev = *(const float4*)&be2[nt * 16 + quad * 4];
        const float4 cbv = *(const float4*)&cb2[nt * 16 + quad * 4];
        const float4 mv  = *(const float4*)&m2[nt * 16 + quad * 4];
        float inv[4], sh[4];
        inv[0] = gv.x * rsqrtf(vv.x + 1e-5f); sh[0] = bev.x + (cbv.x - mv.x) * inv[0];
        inv[1] = gv.y * rsqrtf(vv.y + 1e-5f); sh[1] = bev.y + (cbv.y - mv.y) * inv[1];
        inv[2] = gv.z * rsqrtf(vv.z + 1e-5f); sh[2] = bev.z + (cbv.z - mv.z) * inv[2];
        inv[3] = gv.w * rsqrtf(vv.w + 1e-5f); sh[3] = bev.w + (cbv.w - mv.w) * inv[3];
        #pragma unroll
        for (int rt = 0; rt < 2; rt++) {
            us4 pk;
            #pragma unroll
            for (int r = 0; r < 4; r++) {
                float y = acc2[nt][rt][r] * inv[r] + sh[r];
                y = y > 0.f ? y : 0.f;
                pk[r] = f2b(y);
            }
            *(us4*)&Ts[(rt * 16 + lc) * 72 + nt * 16 + quad * 4] = pk;
        }
    }
    bf16x8 aH[2][2];
    #pragma unroll
    for (int rt = 0; rt < 2; rt++)
        #pragma unroll
        for (int kc = 0; kc < 2; kc++)
            aH[rt][kc] = *(const bf16x8*)&Ts[(rt * 16 + lc) * 72 + kc * 32 + quad * 8];

    // ---- P3b: q (regs) then k (straight into slab Kf, never held) --------
    bf16x8 aQ[2][2];
    for (int p = 0; p < 2; p++) {
        const unsigned short* wsrc = p ? wkp : wqp;
        const float* bsrc = p ? bk : bq;
        const float bscl = p ? 1.0f : 0.125f;
        #pragma unroll
        for (int nt = 0; nt < 4; nt++) {
            bf16x8 aW[2];
            #pragma unroll
            for (int kc = 0; kc < 2; kc++)
                aW[kc] = *(const bf16x8*)(wsrc + (nt * 16 + lc) * 64 + kc * 32 + quad * 8);
            float4 bb = *(const float4*)&bsrc[nt * 16 + quad * 4];
            bb.x *= bscl; bb.y *= bscl; bb.z *= bscl; bb.w *= bscl;
            #pragma unroll
            for (int rt = 0; rt < 2; rt++) {
                f32x4 a = {0.f, 0.f, 0.f, 0.f};
                a = __builtin_amdgcn_mfma_f32_16x16x32_bf16(aW[0], aH[rt][0], a, 0, 0, 0);
                a = __builtin_amdgcn_mfma_f32_16x16x32_bf16(aW[1], aH[rt][1], a, 0, 0, 0);
                us4 pk;
                pk[0] = f2b(a[0] + bb.x); pk[1] = f2b(a[1] + bb.y);
                pk[2] = f2b(a[2] + bb.z); pk[3] = f2b(a[3] + bb.w);
                *(us4*)&Ts[(rt * 16 + lc) * 72 + nt * 16 + quad * 4] = pk;
            }
        }
        #pragma unroll
        for (int rt = 0; rt < 2; rt++)
            #pragma unroll
            for (int kc = 0; kc < 2; kc++) {
                bf16x8 fr = *(const bf16x8*)&Ts[(rt * 16 + lc) * 72 + kc * 32 + quad * 8];
                if (p == 0) aQ[rt][kc] = fr;
                else *(bf16x8*)&Kf[((rt * 2 + kc) << 9) + lane * 8] = fr;  // lane-linear
            }
    }

    // ---- P3c: v -> Vf in B-frag lane-linear order (frag stride 512!) -----
    // C elem (key=rt*16+quad*4+reg, d=nt*16+lc) -> Vf[nt*512 + (key>>3)*128
    //   + lc*8 + (key&7)], i.e. frag nt readable at &Vf[nt*512 + lane*8].
    #pragma unroll
    for (int nt = 0; nt < 4; nt++) {
        bf16x8 bW[2];
        #pragma unroll
        for (int kc = 0; kc < 2; kc++)
            bW[kc] = *(const bf16x8*)(wvp + (nt * 16 + lc) * 64 + kc * 32 + quad * 8);
        const float bvv = bvp[nt * 16 + lc];
        #pragma unroll
        for (int rt = 0; rt < 2; rt++) {
            f32x4 a = {0.f, 0.f, 0.f, 0.f};
            a = __builtin_amdgcn_mfma_f32_16x16x32_bf16(aH[rt][0], bW[0], a, 0, 0, 0);
            a = __builtin_amdgcn_mfma_f32_16x16x32_bf16(aH[rt][1], bW[1], a, 0, 0, 0);
            us4 pk;
            pk[0] = f2b(a[0] + bvv); pk[1] = f2b(a[1] + bvv);
            pk[2] = f2b(a[2] + bvv); pk[3] = f2b(a[3] + bvv);
            *(us4*)&Vf[nt * 512 + ((rt * 2 + (quad >> 1)) * 16 + lc) * 8 + (quad & 1) * 4] = pk;
        }
    }

    __syncthreads();          // all waves' Kf/Vf ready — the ONLY pre-attn barrier

    // ---- attention: single pass, 16 chunks of 32 keys, zero barriers -----
    f32x4 outacc[2][4];
    #pragma unroll
    for (int rt = 0; rt < 2; rt++)
        #pragma unroll
        for (int dt = 0; dt < 4; dt++) outacc[rt][dt] = (f32x4){0.f, 0.f, 0.f, 0.f};
    float den[2][4] = {{0.f, 0.f, 0.f, 0.f}, {0.f, 0.f, 0.f, 0.f}};

    for (int cc = 0; cc < 16; cc++) {
        const unsigned short* sK = (const unsigned short*)(smem + cc * SLAB);
        const unsigned short* sV = (const unsigned short*)(smem + cc * SLAB + 4096);
        bf16x8 bK[2][2];
        #pragma unroll
        for (int nt = 0; nt < 2; nt++)
            #pragma unroll
            for (int kc = 0; kc < 2; kc++)
                bK[nt][kc] = *(const bf16x8*)&sK[((nt * 2 + kc) << 9) + lane * 8];
        bf16x8 bV[4];
        #pragma unroll
        for (int dt = 0; dt < 4; dt++)
            bV[dt] = *(const bf16x8*)&sV[dt * 512 + lane * 8];
        #pragma unroll
        for (int rt = 0; rt < 2; rt++) {
            #pragma unroll
            for (int nt = 0; nt < 2; nt++) {
                f32x4 sv = {0.f, 0.f, 0.f, 0.f};
                sv = __builtin_amdgcn_mfma_f32_16x16x32_bf16(aQ[rt][0], bK[nt][0], sv, 0, 0, 0);
                sv = __builtin_amdgcn_mfma_f32_16x16x32_bf16(aQ[rt][1], bK[nt][1], sv, 0, 0, 0);
                #pragma unroll
                for (int reg = 0; reg < 4; reg++) {
                    float pr = __expf(sv[reg]);           // q pre-scaled by 1/8
                    den[rt][reg] += pr;
                    Ps[(quad * 4 + reg) * 40 + nt * 16 + lc] = f2b(pr);
                }
            }
            bf16x8 aP = *(const bf16x8*)&Ps[lc * 40 + quad * 8];  // C->A round-trip
            #pragma unroll
            for (int dt = 0; dt < 4; dt++)
                outacc[rt][dt] = __builtin_amdgcn_mfma_f32_16x16x32_bf16(
                    aP, bV[dt], outacc[rt][dt], 0, 0, 0);
        }
    }

    // ---- epilogue: den reduce, pooled over the wave's 32 rows ------------
    #pragma unroll
    for (int rt = 0; rt < 2; rt++)
        #pragma unroll
        for (int reg = 0; reg < 4; reg++) {
            float d2 = den[rt][reg];
            d2 += __shfl_xor(d2, 1);  d2 += __shfl_xor(d2, 2);
            d2 += __shfl_xor(d2, 4);  d2 += __shfl_xor(d2, 8);
            den[rt][reg] = d2;
        }
    #pragma unroll
    for (int dt = 0; dt < 4; dt++) {
        float ps = 0.f;
        #pragma unroll
        for (int rt = 0; rt < 2; rt++)
            #pragma unroll
            for (int reg = 0; reg < 4; reg++)
                ps += outacc[rt][dt][reg] / den[rt][reg];
        ps += __shfl_xor(ps, 16);
        ps += __shfl_xor(ps, 32);
        if (quad == 0) red[w * 64 + dt * 16 + lc] = ps;
    }
    __syncthreads();
    if (t < 64) {
        float s = 0.f;
        #pragma unroll
        for (int ww = 0; ww < 16; ww++) s += red[ww * 64 + t];
        pooled[t] = s * (1.0f / 512.0f);
    }
    __syncthreads();
    if (t < NCLASS) {
        float acc = fcb[t];
        #pragma unroll
        for (int d = 0; d < 64; d++) acc += pooled[d] * fcw[t * 64 + d];
        outp[b * NCLASS + t] = acc;
    }
}

// ---------------------------------------------------------------------------
extern "C" void kernel_launch(void* const* d_in, const int* in_sizes, int n_in,
                              void* d_out, int out_size, void* d_ws, size_t ws_size,
                              hipStream_t stream)
{
    const float* x   = (const float*)d_in[0];
    const float* w1  = (const float*)d_in[1];
    const float* cb1 = (const float*)d_in[2];
    const float* g1  = (const float*)d_in[3];
    const float* be1 = (const float*)d_in[4];
    const float* m1  = (const float*)d_in[5];
    const float* v1  = (const float*)d_in[6];
    const float* w2  = (const float*)d_in[7];
    const float* cb2 = (const float*)d_in[8];
    const float* g2  = (const float*)d_in[9];
    const float* be2 = (const float*)d_in[10];
    const float* m2  = (const float*)d_in[11];
    const float* v2  = (const float*)d_in[12];
    const float* wq  = (const float*)d_in[13];
    const float* bq  = (const float*)d_in[14];
    const float* wk  = (const float*)d_in[15];
    const float* bk  = (const float*)d_in[16];
    const float* wv  = (const float*)d_in[17];
    const float* bv  = (const float*)d_in[18];
    const float* fcw = (const float*)d_in[19];
    const float* fcb = (const float*)d_in[20];
    float* out = (float*)d_out;

    char* ws = (char*)d_ws;
    unsigned short* w2p = (unsigned short*)(ws);            // 12,288 B
    unsigned short* wqp = (unsigned short*)(ws + 12288u);   // 8,192 B
    unsigned short* wkp = (unsigned short*)(ws + 20480u);   // 8,192 B
    unsigned short* wvp = (unsigned short*)(ws + 28672u);   // 8,192 B

    prep_weights<<<dim3(1), 256, 0, stream>>>(w2, wq, wk, wv, w2p, wqp, wkp, wvp);
    fused_all<<<dim3(NB), 1024, 0, stream>>>(x, w1, cb1, g1, be1, m1, v1,
                                             cb2, g2, be2, m2, v2,
                                             bq, bk, bv,
                                             w2p, wqp, wkp, wvp,
                                             fcw, fcb, out);
}

// Round 12
// 136.610 us; speedup vs baseline: 1.4072x; 1.0912x over previous
//
#include <hip/hip_runtime.h>
#include <hip/hip_bf16.h>

// B=256, C_IN=6, L=512, C1=32, C2=D=64, NCLASS=10.
// Megakernel v3: one block per batch (1024 thr = 16 waves, 32 L-rows/wave).
// conv1 now MFMA (im2col K=18 pad 32, bn1 folded into w1p/b1f), bn2 folded
// into w2p/b2f. Distributed K/V slabs; attention single pass, K-frag register
// prefetch across chunks; Ps round trip reordered to hide DS latency.
// LDS 151.6 KB. ws: prepped weights only.

#define NB 256
#define LL 512
#define CIN 6
#define NCLASS 10
#define SLAB 9472

typedef __bf16 bf16x8 __attribute__((ext_vector_type(8)));
typedef float f32x4 __attribute__((ext_vector_type(4)));
typedef unsigned short us4 __attribute__((ext_vector_type(4)));

static __device__ __forceinline__ unsigned short f2b(float f) {
    __bf16 h = (__bf16)f;                       // RNE f32->bf16
    return __builtin_bit_cast(unsigned short, h);
}

// ---------------------------------------------------------------------------
// Kernel P: fold BN into weights, convert to bf16 (~3 us, 1 block).
// w1p[c][k=ci*3+dl, pad to 32] * inv1[c]; b1f = be1+(cb1-m1)*inv1.
// w2p[c2][k'=dl*32+ci] * inv2[c2]; b2f = be2+(cb2-m2)*inv2.
// wqp = wq*0.125 (folds 1/sqrt(64)); wkp; wvp.
// ---------------------------------------------------------------------------
__global__ __launch_bounds__(256) void prep_weights(
    const float* __restrict__ w1, const float* __restrict__ cb1,
    const float* __restrict__ g1, const float* __restrict__ be1,
    const float* __restrict__ m1, const float* __restrict__ v1,
    const float* __restrict__ w2, const float* __restrict__ cb2,
    const float* __restrict__ g2, const float* __restrict__ be2,
    const float* __restrict__ m2, const float* __restrict__ v2,
    const float* __restrict__ wq, const float* __restrict__ wk,
    const float* __restrict__ wv,
    unsigned short* __restrict__ w1p, float* __restrict__ b1f,
    unsigned short* __restrict__ w2p, float* __restrict__ b2f,
    unsigned short* __restrict__ wqp, unsigned short* __restrict__ wkp,
    unsigned short* __restrict__ wvp)
{
    const int t = threadIdx.x;
    for (int idx = t; idx < 1024; idx += 256) {       // w1p [32][32]
        int c = idx >> 5, k = idx & 31;
        float inv = g1[c] * rsqrtf(v1[c] + 1e-5f);
        float val = (k < 18) ? w1[c * 18 + k] * inv : 0.f;
        w1p[idx] = f2b(val);
    }
    if (t < 32) {
        float inv = g1[t] * rsqrtf(v1[t] + 1e-5f);
        b1f[t] = be1[t] + (cb1[t] - m1[t]) * inv;
    }
    for (int idx = t; idx < 2048; idx += 256) {       // w2p [64][96]
        int c2 = idx >> 5, ci = idx & 31;
        float inv = g2[c2] * rsqrtf(v2[c2] + 1e-5f);
        const float* wp = w2 + c2 * 96 + ci * 3;
        w2p[c2 * 96 +      ci] = f2b(wp[0] * inv);
        w2p[c2 * 96 + 32 + ci] = f2b(wp[1] * inv);
        w2p[c2 * 96 + 64 + ci] = f2b(wp[2] * inv);
    }
    if (t >= 64 && t < 128) {
        int c2 = t - 64;
        float inv = g2[c2] * rsqrtf(v2[c2] + 1e-5f);
        b2f[c2] = be2[c2] + (cb2[c2] - m2[c2]) * inv;
    }
    for (int idx = t; idx < 4096; idx += 256) {
        wqp[idx] = f2b(wq[idx] * 0.125f);
        wkp[idx] = f2b(wk[idx]);
        wvp[idx] = f2b(wv[idx]);
    }
}

// ---------------------------------------------------------------------------
// Megakernel v3. Slab (9472 B/wave), aliased phases (same-wave in-order DS):
//   conv: xim[48][32] bf16 @0 (3072) | h1sl[34][40] @3072 (2720) | Ts[32][72] @4608
//   attn: Kf @0 (4096) | Vf @4096 (4096) | Ps[16][40] @8192 (1280)
//   epi : redw f32[64] @8192 (aliases Ps, dead) ; pooled @ smem+8448 (slab0)
// ---------------------------------------------------------------------------
__global__ __launch_bounds__(1024, 4) void fused_all(
    const float* __restrict__ x,
    const unsigned short* __restrict__ w1p, const float* __restrict__ b1f,
    const unsigned short* __restrict__ w2p, const float* __restrict__ b2f,
    const unsigned short* __restrict__ wqp, const unsigned short* __restrict__ wkp,
    const unsigned short* __restrict__ wvp,
    const float* __restrict__ bq, const float* __restrict__ bk,
    const float* __restrict__ bvp,
    const float* __restrict__ fcw, const float* __restrict__ fcb,
    float* __restrict__ outp)
{
    const int b = blockIdx.x;
    const int t = threadIdx.x;
    const int w = t >> 6, lane = t & 63, quad = lane >> 4, lc = lane & 15;

    __shared__ __align__(16) char smem[16 * SLAB];   // 151552 B
    char* myslab = smem + w * SLAB;
    unsigned short* xim  = (unsigned short*)myslab;
    unsigned short* h1sl = (unsigned short*)(myslab + 3072);
    unsigned short* Ts   = (unsigned short*)(myslab + 4608);
    unsigned short* Kf   = (unsigned short*)myslab;
    unsigned short* Vf   = (unsigned short*)(myslab + 4096);
    unsigned short* Ps   = (unsigned short*)(myslab + 8192);
    float* redw   = (float*)(myslab + 8192);         // epilogue alias of Ps
    float* pooled = (float*)(smem + 8448);           // slab0, after wave0 redw

    // ---- P0: build im2col A in LDS: xim[j][k=ci*3+dl] = x[ci][w*32-2+j+dl]
    for (int i = lane; i < 384; i += 64)             // zero 48x32 (incl. k>=18 pad)
        *(us4*)&xim[i * 4] = (us4){0, 0, 0, 0};
    for (int i = lane; i < 612; i += 64) {           // 34*18 real entries
        int j = i / 18, k = i - j * 18;
        int ci = k / 3, dl = k - ci * 3;
        int l = w * 32 - 2 + j + dl;
        float val = (l >= 0 && l < LL) ? x[((size_t)b * CIN + ci) * LL + l] : 0.f;
        xim[j * 32 + k] = f2b(val);
    }

    // ---- P1: conv1 as MFMA (M=48 rows x N=32 ch, K=32) + bias + relu -----
    bf16x8 bW1[2];
    #pragma unroll
    for (int nt = 0; nt < 2; nt++)
        bW1[nt] = *(const bf16x8*)(w1p + (nt * 16 + lc) * 32 + quad * 8);
    float b1v[2] = {b1f[lc], b1f[16 + lc]};
    f32x4 h1acc[3][2];
    #pragma unroll
    for (int mt = 0; mt < 3; mt++) {
        bf16x8 aX = *(const bf16x8*)&xim[(mt * 16 + lc) * 32 + quad * 8];
        #pragma unroll
        for (int nt = 0; nt < 2; nt++) {
            f32x4 z = {0.f, 0.f, 0.f, 0.f};
            h1acc[mt][nt] = __builtin_amdgcn_mfma_f32_16x16x32_bf16(aX, bW1[nt], z, 0, 0, 0);
        }
    }
    #pragma unroll
    for (int mt = 0; mt < 3; mt++)
        #pragma unroll
        for (int nt = 0; nt < 2; nt++)
            #pragma unroll
            for (int r = 0; r < 4; r++) {
                int j = mt * 16 + quad * 4 + r;
                if (j < 34) {
                    int pos = w * 32 - 1 + j;
                    float y = h1acc[mt][nt][r] + b1v[nt];
                    y = (pos >= 0 && pos < LL && y > 0.f) ? y : 0.f;
                    h1sl[j * 40 + nt * 16 + lc] = f2b(y);
                }
            }

    // ---- P2: conv2 as GEMM (M=64 c2, N=32 rows, K=96; k'=dl*32+ci) -------
    bf16x8 bX[2][3], aW2[4][3];
    #pragma unroll
    for (int rt = 0; rt < 2; rt++)
        #pragma unroll
        for (int kc = 0; kc < 3; kc++)
            bX[rt][kc] = *(const bf16x8*)&h1sl[(rt * 16 + lc + kc) * 40 + quad * 8];
    #pragma unroll
    for (int nt = 0; nt < 4; nt++)
        #pragma unroll
        for (int kc = 0; kc < 3; kc++)
            aW2[nt][kc] = *(const bf16x8*)(w2p + (nt * 16 + lc) * 96 + kc * 32 + quad * 8);

    f32x4 acc2[4][2];
    #pragma unroll
    for (int nt = 0; nt < 4; nt++)
        #pragma unroll
        for (int rt = 0; rt < 2; rt++) {
            f32x4 a = {0.f, 0.f, 0.f, 0.f};
            a = __builtin_amdgcn_mfma_f32_16x16x32_bf16(aW2[nt][0], bX[rt][0], a, 0, 0, 0);
            a = __builtin_amdgcn_mfma_f32_16x16x32_bf16(aW2[nt][1], bX[rt][1], a, 0, 0, 0);
            acc2[nt][rt] = __builtin_amdgcn_mfma_f32_16x16x32_bf16(aW2[nt][2], bX[rt][2], a, 0, 0, 0);
        }

    // ---- P3a: +b2f, relu -> Ts[row][c2] ----------------------------------
    #pragma unroll
    for (int nt = 0; nt < 4; nt++) {
        const float4 bb2 = *(const float4*)&b2f[nt * 16 + quad * 4];
        #pragma unroll
        for (int rt = 0; rt < 2; rt++) {
            us4 pk;
            float y0 = acc2[nt][rt][0] + bb2.x; pk[0] = f2b(y0 > 0.f ? y0 : 0.f);
            float y1 = acc2[nt][rt][1] + bb2.y; pk[1] = f2b(y1 > 0.f ? y1 : 0.f);
            float y2 = acc2[nt][rt][2] + bb2.z; pk[2] = f2b(y2 > 0.f ? y2 : 0.f);
            float y3 = acc2[nt][rt][3] + bb2.w; pk[3] = f2b(y3 > 0.f ? y3 : 0.f);
            *(us4*)&Ts[(rt * 16 + lc) * 72 + nt * 16 + quad * 4] = pk;
        }
    }
    bf16x8 aH[2][2];
    #pragma unroll
    for (int rt = 0; rt < 2; rt++)
        #pragma unroll
        for (int kc = 0; kc < 2; kc++)
            aH[rt][kc] = *(const bf16x8*)&Ts[(rt * 16 + lc) * 72 + kc * 32 + quad * 8];

    // ---- P3b: q (regs) then k (straight into slab Kf) --------------------
    bf16x8 aQ[2][2];
    for (int p = 0; p < 2; p++) {
        const unsigned short* wsrc = p ? wkp : wqp;
        const float* bsrc = p ? bk : bq;
        const float bscl = p ? 1.0f : 0.125f;
        #pragma unroll
        for (int nt = 0; nt < 4; nt++) {
            bf16x8 aW[2];
            #pragma unroll
            for (int kc = 0; kc < 2; kc++)
                aW[kc] = *(const bf16x8*)(wsrc + (nt * 16 + lc) * 64 + kc * 32 + quad * 8);
            float4 bb = *(const float4*)&bsrc[nt * 16 + quad * 4];
            bb.x *= bscl; bb.y *= bscl; bb.z *= bscl; bb.w *= bscl;
            #pragma unroll
            for (int rt = 0; rt < 2; rt++) {
                f32x4 a = {0.f, 0.f, 0.f, 0.f};
                a = __builtin_amdgcn_mfma_f32_16x16x32_bf16(aW[0], aH[rt][0], a, 0, 0, 0);
                a = __builtin_amdgcn_mfma_f32_16x16x32_bf16(aW[1], aH[rt][1], a, 0, 0, 0);
                us4 pk;
                pk[0] = f2b(a[0] + bb.x); pk[1] = f2b(a[1] + bb.y);
                pk[2] = f2b(a[2] + bb.z); pk[3] = f2b(a[3] + bb.w);
                *(us4*)&Ts[(rt * 16 + lc) * 72 + nt * 16 + quad * 4] = pk;
            }
        }
        #pragma unroll
        for (int rt = 0; rt < 2; rt++)
            #pragma unroll
            for (int kc = 0; kc < 2; kc++) {
                bf16x8 fr = *(const bf16x8*)&Ts[(rt * 16 + lc) * 72 + kc * 32 + quad * 8];
                if (p == 0) aQ[rt][kc] = fr;
                else *(bf16x8*)&Kf[((rt * 2 + kc) << 9) + lane * 8] = fr;
            }
    }

    // ---- P3c: v -> Vf, B-frag lane-linear (frag stride 512 shorts) -------
    #pragma unroll
    for (int nt = 0; nt < 4; nt++) {
        bf16x8 bW[2];
        #pragma unroll
        for (int kc = 0; kc < 2; kc++)
            bW[kc] = *(const bf16x8*)(wvp + (nt * 16 + lc) * 64 + kc * 32 + quad * 8);
        const float bvv = bvp[nt * 16 + lc];
        #pragma unroll
        for (int rt = 0; rt < 2; rt++) {
            f32x4 a = {0.f, 0.f, 0.f, 0.f};
            a = __builtin_amdgcn_mfma_f32_16x16x32_bf16(aH[rt][0], bW[0], a, 0, 0, 0);
            a = __builtin_amdgcn_mfma_f32_16x16x32_bf16(aH[rt][1], bW[1], a, 0, 0, 0);
            us4 pk;
            pk[0] = f2b(a[0] + bvv); pk[1] = f2b(a[1] + bvv);
            pk[2] = f2b(a[2] + bvv); pk[3] = f2b(a[3] + bvv);
            *(us4*)&Vf[nt * 512 + ((rt * 2 + (quad >> 1)) * 16 + lc) * 8 + (quad & 1) * 4] = pk;
        }
    }

    __syncthreads();          // all waves' Kf/Vf ready — only pre-attn barrier

    // ---- attention: single pass, 16 chunks, K-frag register prefetch -----
    f32x4 outacc[2][4];
    #pragma unroll
    for (int rt = 0; rt < 2; rt++)
        #pragma unroll
        for (int dt = 0; dt < 4; dt++) outacc[rt][dt] = (f32x4){0.f, 0.f, 0.f, 0.f};
    float den[2][4] = {{0.f, 0.f, 0.f, 0.f}, {0.f, 0.f, 0.f, 0.f}};

    bf16x8 bK[2][2], bKn[2][2];
    {
        const unsigned short* sK = (const unsigned short*)smem;   // chunk 0
        #pragma unroll
        for (int nt = 0; nt < 2; nt++)
            #pragma unroll
            for (int kc = 0; kc < 2; kc++)
                bK[nt][kc] = *(const bf16x8*)&sK[((nt * 2 + kc) << 9) + lane * 8];
    }

    for (int cc = 0; cc < 16; cc++) {
        // QK both rt (8 MFMAs) on current bK
        f32x4 sv[2][2];
        #pragma unroll
        for (int rt = 0; rt < 2; rt++)
            #pragma unroll
            for (int nt = 0; nt < 2; nt++) {
                f32x4 z = {0.f, 0.f, 0.f, 0.f};
                z = __builtin_amdgcn_mfma_f32_16x16x32_bf16(aQ[rt][0], bK[nt][0], z, 0, 0, 0);
                sv[rt][nt] = __builtin_amdgcn_mfma_f32_16x16x32_bf16(aQ[rt][1], bK[nt][1], z, 0, 0, 0);
            }
        // current V frags
        const unsigned short* sV = (const unsigned short*)(smem + cc * SLAB + 4096);
        bf16x8 bV[4];
        #pragma unroll
        for (int dt = 0; dt < 4; dt++)
            bV[dt] = *(const bf16x8*)&sV[dt * 512 + lane * 8];
        // exp rt0 -> Ps
        #pragma unroll
        for (int nt = 0; nt < 2; nt++)
            #pragma unroll
            for (int reg = 0; reg < 4; reg++) {
                float pr = __expf(sv[0][nt][reg]);    // q pre-scaled by 1/8
                den[0][reg] += pr;
                Ps[(quad * 4 + reg) * 40 + nt * 16 + lc] = f2b(pr);
            }
        // prefetch next chunk's K frags (latency hidden behind round trip)
        if (cc < 15) {
            const unsigned short* sKn = (const unsigned short*)(smem + (cc + 1) * SLAB);
            #pragma unroll
            for (int nt = 0; nt < 2; nt++)
                #pragma unroll
                for (int kc = 0; kc < 2; kc++)
                    bKn[nt][kc] = *(const bf16x8*)&sKn[((nt * 2 + kc) << 9) + lane * 8];
        }
        bf16x8 aP0 = *(const bf16x8*)&Ps[lc * 40 + quad * 8];
        // exp rt1 -> Ps (VALU fills the aP0 wait shadow; in-order pipe keeps aP0 safe)
        #pragma unroll
        for (int nt = 0; nt < 2; nt++)
            #pragma unroll
            for (int reg = 0; reg < 4; reg++) {
                float pr = __expf(sv[1][nt][reg]);
                den[1][reg] += pr;
                Ps[(quad * 4 + reg) * 40 + nt * 16 + lc] = f2b(pr);
            }
        #pragma unroll
        for (int dt = 0; dt < 4; dt++)
            outacc[0][dt] = __builtin_amdgcn_mfma_f32_16x16x32_bf16(aP0, bV[dt], outacc[0][dt], 0, 0, 0);
        bf16x8 aP1 = *(const bf16x8*)&Ps[lc * 40 + quad * 8];
        #pragma unroll
        for (int dt = 0; dt < 4; dt++)
            outacc[1][dt] = __builtin_amdgcn_mfma_f32_16x16x32_bf16(aP1, bV[dt], outacc[1][dt], 0, 0, 0);
        #pragma unroll
        for (int nt = 0; nt < 2; nt++)
            #pragma unroll
            for (int kc = 0; kc < 2; kc++)
                bK[nt][kc] = bKn[nt][kc];
    }

    // ---- epilogue: den reduce (quad 16-lane classes), pooled, fc ---------
    float rden[2][4];
    #pragma unroll
    for (int rt = 0; rt < 2; rt++)
        #pragma unroll
        for (int reg = 0; reg < 4; reg++) {
            float d2 = den[rt][reg];
            d2 += __shfl_xor(d2, 1);  d2 += __shfl_xor(d2, 2);
            d2 += __shfl_xor(d2, 4);  d2 += __shfl_xor(d2, 8);
            rden[rt][reg] = 1.0f / d2;
        }
    #pragma unroll
    for (int dt = 0; dt < 4; dt++) {
        float ps = 0.f;
        #pragma unroll
        for (int rt = 0; rt < 2; rt++)
            #pragma unroll
            for (int reg = 0; reg < 4; reg++)
                ps += outacc[rt][dt][reg] * rden[rt][reg];
        ps += __shfl_xor(ps, 16);
        ps += __shfl_xor(ps, 32);
        if (quad == 0) redw[dt * 16 + lc] = ps;     // aliases dead Ps
    }
    __syncthreads();
    if (t < 64) {
        float s = 0.f;
        #pragma unroll
        for (int ww = 0; ww < 16; ww++)
            s += *(const float*)(smem + ww * SLAB + 8192 + t * 4);
        pooled[t] = s * (1.0f / 512.0f);
    }
    __syncthreads();
    if (t < NCLASS) {
        float acc = fcb[t];
        #pragma unroll
        for (int d = 0; d < 64; d++) acc += pooled[d] * fcw[t * 64 + d];
        outp[b * NCLASS + t] = acc;
    }
}

// ---------------------------------------------------------------------------
extern "C" void kernel_launch(void* const* d_in, const int* in_sizes, int n_in,
                              void* d_out, int out_size, void* d_ws, size_t ws_size,
                              hipStream_t stream)
{
    const float* x   = (const float*)d_in[0];
    const float* w1  = (const float*)d_in[1];
    const float* cb1 = (const float*)d_in[2];
    const float* g1  = (const float*)d_in[3];
    const float* be1 = (const float*)d_in[4];
    const float* m1  = (const float*)d_in[5];
    const float* v1  = (const float*)d_in[6];
    const float* w2  = (const float*)d_in[7];
    const float* cb2 = (const float*)d_in[8];
    const float* g2  = (const float*)d_in[9];
    const float* be2 = (const float*)d_in[10];
    const float* m2  = (const float*)d_in[11];
    const float* v2  = (const float*)d_in[12];
    const float* wq  = (const float*)d_in[13];
    const float* bq  = (const float*)d_in[14];
    const float* wk  = (const float*)d_in[15];
    const float* bk  = (const float*)d_in[16];
    const float* wv  = (const float*)d_in[17];
    const float* bv  = (const float*)d_in[18];
    const float* fcw = (const float*)d_in[19];
    const float* fcb = (const float*)d_in[20];
    float* out = (float*)d_out;

    char* ws = (char*)d_ws;
    unsigned short* w1p = (unsigned short*)(ws);            // 2048 B
    float*          b1f = (float*)(ws + 2048u);             // 128 B
    float*          b2f = (float*)(ws + 2176u);             // 256 B
    unsigned short* w2p = (unsigned short*)(ws + 2432u);    // 12288 B
    unsigned short* wqp = (unsigned short*)(ws + 14720u);   // 8192 B
    unsigned short* wkp = (unsigned short*)(ws + 22912u);   // 8192 B
    unsigned short* wvp = (unsigned short*)(ws + 31104u);   // 8192 B

    prep_weights<<<dim3(1), 256, 0, stream>>>(w1, cb1, g1, be1, m1, v1,
                                              w2, cb2, g2, be2, m2, v2,
                                              wq, wk, wv,
                                              w1p, b1f, w2p, b2f, wqp, wkp, wvp);
    fused_all<<<dim3(NB), 1024, 0, stream>>>(x, w1p, b1f, w2p, b2f,
                                             wqp, wkp, wvp,
                                             bq, bk, bv, fcw, fcb, out);
}